// Round 14
// baseline (358.042 us; speedup 1.0000x reference)
//
#include <hip/hip_runtime.h>
#include <hip/hip_cooperative_groups.h>
#include <cstddef>

namespace cg = cooperative_groups;

#define NB 8
#define NN 1024
#define NF 32
#define NIDX 4

// ---- ws layout (float offsets), shared by coop + fallback paths ----
#define OFF_ROW   0u
#define OFF_COLP  8192u          // [64][8192]
#define OFF_DINV  532480u
#define OFF_S     540672u        // fallback svec [8192][8]
#define OFF_P     606208u
#define OFF_R     671744u
#define OFF_WP    737280u        // coop: [2][65536]; fallback: [4][65536]

#if __has_builtin(__builtin_amdgcn_sinf)
#define FSIN(x) __builtin_amdgcn_sinf(x)   // sin(2*pi*x), |x|<0.5 here
#define FCOS(x) __builtin_amdgcn_cosf(x)
#else
#define FSIN(x) __sinf((x) * 6.283185307179586f)
#define FCOS(x) __cosf((x) * 6.283185307179586f)
#endif

#define TRIG6(dd, csv, snv)                                          \
  float s4 = FSIN(0.25f*(dd)), c4w = FCOS(0.25f*(dd));               \
  float s3 = FSIN((1.f/3.f)*(dd)), c3 = FCOS((1.f/3.f)*(dd));        \
  float s5 = FSIN(0.2f*(dd)), c5 = FCOS(0.2f*(dd));                  \
  float c2 = 1.f - 2.f*s4*s4, s2 = 2.f*s4*c4w;                       \
  csv[0]=c2; csv[1]=c3; csv[2]=c4w; csv[3]=c5;                       \
  snv[0]=s2; snv[1]=s3; snv[2]=s4; snv[3]=s5;

// 8x8 in-wave transpose-reduce (R4/R11-verified): lane ends with slot (lane&7)
// of i-step s summed over its 8-lane group; result -> red[w].
#define TREDUCE(accr, acci, red, w, lane, b1, b2, b4)                \
  _Pragma("unroll")                                                  \
  for (int s = 0; s < 8; ++s) {                                      \
    float v0 = accr[s][0], v1 = acci[s][0], v2 = accr[s][1], v3 = acci[s][1]; \
    float v4 = accr[s][2], v5 = acci[s][2], v6 = accr[s][3], v7 = acci[s][3]; \
    float k0 = b1 ? v1 : v0, s0 = b1 ? v0 : v1;                      \
    float k1 = b1 ? v3 : v2, s1 = b1 ? v2 : v3;                      \
    float k2 = b1 ? v5 : v4, s2_ = b1 ? v4 : v5;                     \
    float k3 = b1 ? v7 : v6, s3_ = b1 ? v6 : v7;                     \
    v0 = k0 + __shfl_xor(s0, 1);                                     \
    v1 = k1 + __shfl_xor(s1, 1);                                     \
    v2 = k2 + __shfl_xor(s2_, 1);                                    \
    v3 = k3 + __shfl_xor(s3_, 1);                                    \
    k0 = b2 ? v1 : v0; s0 = b2 ? v0 : v1;                            \
    k1 = b2 ? v3 : v2; s1 = b2 ? v2 : v3;                            \
    v0 = k0 + __shfl_xor(s0, 2);                                     \
    v1 = k1 + __shfl_xor(s1, 2);                                     \
    k0 = b4 ? v1 : v0; s0 = b4 ? v0 : v1;                            \
    v0 = k0 + __shfl_xor(s0, 4);                                     \
    red[w][s*72 + (lane & 7)*9 + (lane >> 3)] = v0;                  \
  }

// ================= cooperative single-dispatch kernel =================
// 512 blocks x 256 thr; bid%8 == batch b in EVERY phase (XCD-pinned).
// A: row+col sums  B: dinv+contractions, out=s+bias  C: wpart=halfM(rvec)
// D: out += halfM(dinv*(p+wpart0+wpart1))
__global__ __launch_bounds__(256, 4) void k_all(
    const float* __restrict__ Xr, const float* __restrict__ Xi,
    const float* __restrict__ adj, const float* __restrict__ weight,
    const float* __restrict__ bias,
    float* __restrict__ rowsum, float* __restrict__ colpart,
    float* __restrict__ dinv, float* __restrict__ pvec, float* __restrict__ rvec,
    float* __restrict__ wpart, float* __restrict__ out) {
  cg::grid_group grid = cg::this_grid();
  __shared__ union U {
    float cacc[4][NN];                                             // A: 16 KB
    struct { float Tjs[64][33]; float vlds[512][8]; float red[4][576]; } p;  // C/D: 33.6 KB
  } smu;
  int bid = blockIdx.x;
  int t = threadIdx.x, lane = t & 63, w = t >> 6;
  int wu = __builtin_amdgcn_readfirstlane(w);
  int b = bid & 7;

  // ---------------- Phase A ----------------
  {
    int strip = bid >> 3;                       // 0..63, 16 rows each
    float colreg[16];
    #pragma unroll
    for (int i = 0; i < 16; ++i) colreg[i] = 0.f;
    int r0 = strip*16 + w*4;
    #pragma unroll
    for (int rr = 0; rr < 4; ++rr) {
      const float4* row4 = reinterpret_cast<const float4*>(adj + ((size_t)b*NN + r0 + rr)*NN);
      float rs = 0.f;
      #pragma unroll
      for (int cq = 0; cq < 4; ++cq) {
        float4 v = row4[cq*64 + lane];
        colreg[cq*4+0] += v.x; colreg[cq*4+1] += v.y;
        colreg[cq*4+2] += v.z; colreg[cq*4+3] += v.w;
        rs += (v.x + v.y) + (v.z + v.w);
      }
      #pragma unroll
      for (int o = 32; o > 0; o >>= 1) rs += __shfl_xor(rs, o);
      if (lane == 0) rowsum[b*NN + r0 + rr] = rs;
    }
    #pragma unroll
    for (int cq = 0; cq < 4; ++cq)
      #pragma unroll
      for (int x = 0; x < 4; ++x) smu.cacc[w][cq*256 + lane*4 + x] = colreg[cq*4+x];
    __syncthreads();
    for (int c = t; c < NN; c += 256) {
      float s = smu.cacc[0][c] + smu.cacc[1][c] + smu.cacc[2][c] + smu.cacc[3][c];
      colpart[(size_t)strip*(NB*NN) + b*NN + c] = s;
    }
  }
  __threadfence();
  grid.sync();

  // ---------------- Phase B ----------------
  if (bid < 32) {
    int gid = bid*256 + t;
    float cs = 0.f;
    for (int k = 0; k < 64; ++k) cs += colpart[(size_t)k*(NB*NN) + gid];
    float D = 0.5f*(rowsum[gid] + cs);
    float di = (D > 0.f) ? (1.0f / sqrtf(D)) : 0.f;
    dinv[gid] = di;
    const float* xr = Xr + (size_t)gid*NF;
    const float* xi = Xi + (size_t)gid*NF;
    float acc[NIDX][3][2];
    #pragma unroll
    for (int x = 0; x < NIDX; ++x)
      #pragma unroll
      for (int v = 0; v < 3; ++v) { acc[x][v][0] = 0.f; acc[x][v][1] = 0.f; }
    for (int f = 0; f < NF; ++f) {
      float xrf = xr[f], xif = xi[f];
      #pragma unroll
      for (int x = 0; x < NIDX; ++x) {
        float w0 = weight[x*96 + f], w1 = weight[x*96 + 32 + f], w2 = weight[x*96 + 64 + f];
        float av = w0 + w2, bv = w1 + 2.f*w2, cv = -2.f*w2;
        acc[x][0][0] += av*xrf; acc[x][0][1] += av*xif;
        acc[x][1][0] += bv*xrf; acc[x][1][1] += bv*xif;
        acc[x][2][0] += cv*xrf; acc[x][2][1] += cv*xif;
      }
    }
    #pragma unroll
    for (int x = 0; x < NIDX; ++x) {
      size_t o = (size_t)gid*8 + x*2;
      pvec[o] = acc[x][1][0];      pvec[o+1] = acc[x][1][1];
      rvec[o] = di*acc[x][2][0];   rvec[o+1] = di*acc[x][2][1];
      out[gid*4 + x]         = acc[x][0][0] + bias[x];   // real
      out[32768 + gid*4 + x] = acc[x][0][1];             // imag
    }
  }
  __threadfence();
  grid.sync();

  // ---------------- Phases C, D ----------------
  int it = (bid >> 3) & 31, zc = bid >> 8;    // 32-row i-tile, 512-j chunk
  int i0 = it*32, j0base = zc*512;
  int ibase = i0 + wu*8;
  bool b1 = (lane & 1), b2 = (lane & 2), b4 = (lane & 4);

  #pragma unroll 1
  for (int phase = 0; phase < 2; ++phase) {
    if (phase == 1) {
      for (int e = t; e < 512*8; e += 256) {
        int jj = e >> 3, s = e & 7;
        size_t o = ((size_t)b*NN + j0base + jj)*8 + s;
        float v = pvec[o] + wpart[o] + wpart[65536 + o];
        smu.p.vlds[jj][s] = v * dinv[b*NN + j0base + jj];
      }
    }
    float accr[8][NIDX], acci[8][NIDX];
    #pragma unroll
    for (int s = 0; s < 8; ++s)
      #pragma unroll
      for (int x = 0; x < NIDX; ++x) { accr[s][x] = 0.f; acci[s][x] = 0.f; }

    for (int jt = 0; jt < 8; ++jt) {
      int j0 = j0base + jt*64;
      __syncthreads();
      #pragma unroll
      for (int m = 0; m < 2; ++m) {
        int e4 = t + 256*m;                    // 512 float4 = 64j x 32i tile
        int jj = e4 >> 3, i4 = (e4 & 7) << 2;
        float4 vv = *reinterpret_cast<const float4*>(adj + ((size_t)b*NN + j0 + jj)*NN + i0 + i4);
        float* dst = &smu.p.Tjs[jj][i4];
        dst[0] = vv.x; dst[1] = vv.y; dst[2] = vv.z; dst[3] = vv.w;
      }
      float vr[NIDX], vi[NIDX];
      if (phase == 0) {
        const float4* vp = reinterpret_cast<const float4*>(rvec + ((size_t)b*NN + j0 + lane)*8);
        float4 v0 = vp[0], v1 = vp[1];
        vr[0]=v0.x; vi[0]=v0.y; vr[1]=v0.z; vi[1]=v0.w;
        vr[2]=v1.x; vi[2]=v1.y; vr[3]=v1.z; vi[3]=v1.w;
      } else {
        const float4* vp = reinterpret_cast<const float4*>(&smu.p.vlds[jt*64 + lane][0]);
        float4 v0 = vp[0], v1 = vp[1];
        vr[0]=v0.x; vi[0]=v0.y; vr[1]=v0.z; vi[1]=v0.w;
        vr[2]=v1.x; vi[2]=v1.y; vr[3]=v1.z; vi[3]=v1.w;
      }
      __syncthreads();
      const float* arb = adj + ((size_t)b*NN + ibase)*NN + j0 + lane;
      #pragma unroll
      for (int s = 0; s < 8; ++s) {
        float ar = arb[(size_t)s*NN];          // adj[i][j], coalesced
        float ac = smu.p.Tjs[lane][wu*8 + s];  // adj[j][i], 2-way free
        float dd = ar - ac, sm = ar + ac;
        float csv[NIDX], snv[NIDX];
        TRIG6(dd, csv, snv)
        #pragma unroll
        for (int x = 0; x < NIDX; ++x) {
          float A = sm*csv[x], B = sm*snv[x];
          accr[s][x] += A*vr[x] - B*vi[x];
          acci[s][x] += A*vi[x] + B*vr[x];
        }
      }
    }
    TREDUCE(accr, acci, smu.p.red, w, lane, b1, b2, b4)
    __syncthreads();
    {
      int row = lane >> 3, slot = lane & 7;    // wave-local 8 rows x 8 slots
      float sum = 0.f;
      #pragma unroll
      for (int g = 0; g < 8; ++g) sum += smu.p.red[w][row*72 + slot*9 + g];
      int gi = b*NN + ibase + row;
      float val = sum * 0.5f * dinv[gi];
      if (phase == 0) wpart[(size_t)zc*65536 + (size_t)gi*8 + slot] = val;
      else atomicAdd(&out[(slot & 1)*32768 + gi*4 + (slot >> 1)], val);
    }
    if (phase == 0) {
      __threadfence();
      grid.sync();
    }
  }
}

// ================= fallback: R8-proven 4-dispatch path (53.4 us) =================
__global__ __launch_bounds__(512) void fb_sums(const float* __restrict__ adj,
                                               float* __restrict__ rowsum,
                                               float* __restrict__ colpart,
                                               float* __restrict__ out) {
  int b = blockIdx.x, strip = blockIdx.y;
  int t = threadIdx.x, lane = t & 63, w = t >> 6;
  { int zid = blockIdx.x*64 + blockIdx.y;
    if (t < 128) out[zid*128 + t] = 0.f; }
  float colreg[16];
  #pragma unroll
  for (int i = 0; i < 16; ++i) colreg[i] = 0.f;
  int r0 = strip*16 + w*2;
  #pragma unroll
  for (int rr = 0; rr < 2; ++rr) {
    const float4* row4 = reinterpret_cast<const float4*>(adj + ((size_t)b*NN + r0 + rr)*NN);
    float rs = 0.f;
    #pragma unroll
    for (int cq = 0; cq < 4; ++cq) {
      float4 v = row4[cq*64 + lane];
      colreg[cq*4+0] += v.x; colreg[cq*4+1] += v.y;
      colreg[cq*4+2] += v.z; colreg[cq*4+3] += v.w;
      rs += (v.x + v.y) + (v.z + v.w);
    }
    #pragma unroll
    for (int o = 32; o > 0; o >>= 1) rs += __shfl_xor(rs, o);
    if (lane == 0) rowsum[b*NN + r0 + rr] = rs;
  }
  __shared__ float cacc[8][NN];
  #pragma unroll
  for (int cq = 0; cq < 4; ++cq)
    #pragma unroll
    for (int x = 0; x < 4; ++x) cacc[w][cq*256 + lane*4 + x] = colreg[cq*4+x];
  __syncthreads();
  for (int c = t; c < NN; c += 512) {
    float s = 0.f;
    #pragma unroll
    for (int ww = 0; ww < 8; ++ww) s += cacc[ww][c];
    colpart[(size_t)strip*(NB*NN) + b*NN + c] = s;
  }
}

__global__ __launch_bounds__(256) void fb_prep(const float* __restrict__ Xr, const float* __restrict__ Xi,
                       const float* __restrict__ weight,
                       const float* __restrict__ rowsum, const float* __restrict__ colpart,
                       float* __restrict__ dinv,
                       float* __restrict__ svec, float* __restrict__ pvec, float* __restrict__ rvec) {
  __shared__ float wsm[NIDX*3*NF];
  int t = threadIdx.x;
  for (int e = t; e < NIDX*3*NF; e += 256) wsm[e] = weight[e];
  __syncthreads();
  int gid = blockIdx.x*256 + t;
  float cs = 0.f;
  for (int k = 0; k < 64; ++k) cs += colpart[(size_t)k*(NB*NN) + gid];
  float D = 0.5f*(rowsum[gid] + cs);
  float di = (D > 0.f) ? (1.0f / sqrtf(D)) : 0.f;
  dinv[gid] = di;
  const float* xr = Xr + (size_t)gid*NF;
  const float* xi = Xi + (size_t)gid*NF;
  float acc[NIDX][3][2];
  #pragma unroll
  for (int x = 0; x < NIDX; ++x)
    #pragma unroll
    for (int v = 0; v < 3; ++v) { acc[x][v][0] = 0.f; acc[x][v][1] = 0.f; }
  for (int f = 0; f < NF; ++f) {
    float xrf = xr[f], xif = xi[f];
    #pragma unroll
    for (int x = 0; x < NIDX; ++x) {
      float w0 = wsm[x*96 + f], w1 = wsm[x*96 + 32 + f], w2 = wsm[x*96 + 64 + f];
      float av = w0 + w2, bv = w1 + 2.f*w2, cv = -2.f*w2;
      acc[x][0][0] += av*xrf; acc[x][0][1] += av*xif;
      acc[x][1][0] += bv*xrf; acc[x][1][1] += bv*xif;
      acc[x][2][0] += cv*xrf; acc[x][2][1] += cv*xif;
    }
  }
  #pragma unroll
  for (int x = 0; x < NIDX; ++x) {
    size_t o = (size_t)gid*8 + x*2;
    svec[o] = acc[x][0][0];      svec[o+1] = acc[x][0][1];
    pvec[o] = acc[x][1][0];      pvec[o+1] = acc[x][1][1];
    rvec[o] = di*acc[x][2][0];   rvec[o+1] = di*acc[x][2][1];
  }
}

template<int MODE>
__global__ __launch_bounds__(512, 4) void fb_pass(const float* __restrict__ adj,
                                                  const float* __restrict__ dinv,
                                                  const float* __restrict__ vin,
                                                  float* __restrict__ wpart,
                                                  const float* __restrict__ svec,
                                                  const float* __restrict__ bias,
                                                  float* __restrict__ out) {
  __shared__ float Tjs[64][65];
  __shared__ float vlds[256][8];
  __shared__ float red[8][8*72];
  int b = blockIdx.x, i0 = blockIdx.y*64, zc = blockIdx.z;
  int j0base = zc*256;
  int t = threadIdx.x, lane = t & 63;
  int w = t >> 6;
  int wu = __builtin_amdgcn_readfirstlane(w);

  if constexpr (MODE == 1) {
    for (int e = t; e < 256*8; e += 512) {
      int jj = e >> 3, s = e & 7;
      size_t o = ((size_t)b*NN + j0base + jj)*8 + s;
      float v = vin[o];
      #pragma unroll
      for (int c = 0; c < 4; ++c) v += wpart[(size_t)c*65536 + o];
      vlds[jj][s] = v * dinv[b*NN + j0base + jj];
    }
  }
  float accr[8][NIDX], acci[8][NIDX];
  #pragma unroll
  for (int s = 0; s < 8; ++s)
    #pragma unroll
    for (int x = 0; x < NIDX; ++x) { accr[s][x] = 0.f; acci[s][x] = 0.f; }

  for (int jt = 0; jt < 4; ++jt) {
    int j0 = j0base + jt*64;
    __syncthreads();
    #pragma unroll
    for (int m = 0; m < 2; ++m) {
      int e4 = t + 512*m;
      int jj = e4 >> 4, i4 = (e4 & 15) << 2;
      float4 vv = *reinterpret_cast<const float4*>(adj + ((size_t)b*NN + j0 + jj)*NN + i0 + i4);
      float* dst = &Tjs[jj][i4];
      dst[0] = vv.x; dst[1] = vv.y; dst[2] = vv.z; dst[3] = vv.w;
    }
    float vr[NIDX], vi[NIDX];
    if constexpr (MODE == 0) {
      const float4* vb = reinterpret_cast<const float4*>(vin + ((size_t)b*NN + j0 + lane)*8);
      float4 a = vb[0], c = vb[1];
      vr[0]=a.x; vi[0]=a.y; vr[1]=a.z; vi[1]=a.w;
      vr[2]=c.x; vi[2]=c.y; vr[3]=c.z; vi[3]=c.w;
    } else {
      const float4* vb = reinterpret_cast<const float4*>(&vlds[jt*64 + lane][0]);
      float4 a = vb[0], c = vb[1];
      vr[0]=a.x; vi[0]=a.y; vr[1]=a.z; vi[1]=a.w;
      vr[2]=c.x; vi[2]=c.y; vr[3]=c.z; vi[3]=c.w;
    }
    __syncthreads();
    const float* arbase = adj + ((size_t)b*NN + i0 + wu*8)*NN + j0 + lane;
    #pragma unroll
    for (int s = 0; s < 8; ++s) {
      float ar = arbase[(size_t)s*NN];
      float ac = Tjs[lane][wu*8 + s];
      float dd = ar - ac, sm = ar + ac;
      float csv[NIDX], snv[NIDX];
      TRIG6(dd, csv, snv)
      #pragma unroll
      for (int x = 0; x < NIDX; ++x) {
        float A = sm*csv[x], B = sm*snv[x];
        accr[s][x] += A*vr[x] - B*vi[x];
        acci[s][x] += A*vi[x] + B*vr[x];
      }
    }
  }
  bool b1 = (lane & 1), b2 = (lane & 2), b4 = (lane & 4);
  TREDUCE(accr, acci, red, w, lane, b1, b2, b4)
  __syncthreads();
  {
    int iloc = w*8 + (lane >> 3), slot = lane & 7;
    float sum = 0.f;
    #pragma unroll
    for (int g = 0; g < 8; ++g) sum += red[w][(lane >> 3)*72 + slot*9 + g];
    int i = i0 + iloc;
    float val = sum * 0.5f * dinv[b*NN + i];
    if constexpr (MODE == 0) {
      wpart[(size_t)zc*65536 + ((size_t)b*NN + i)*8 + slot] = val;
    } else {
      if (zc == 0) {
        val += svec[((size_t)b*NN + i)*8 + slot];
        if ((slot & 1) == 0) val += bias[slot >> 1];
      }
      atomicAdd(&out[(slot & 1)*32768 + b*4096 + i*4 + (slot >> 1)], val);
    }
  }
}

extern "C" void kernel_launch(void* const* d_in, const int* in_sizes, int n_in,
                              void* d_out, int out_size, void* d_ws, size_t ws_size,
                              hipStream_t stream) {
  (void)in_sizes; (void)n_in; (void)out_size; (void)ws_size;
  const float* Xr     = (const float*)d_in[0];
  const float* Xi     = (const float*)d_in[1];
  const float* adj    = (const float*)d_in[2];
  const float* weight = (const float*)d_in[3];
  const float* bias   = (const float*)d_in[4];
  float* ws = (float*)d_ws;
  float* rowsum  = ws + OFF_ROW;
  float* colpart = ws + OFF_COLP;
  float* dinv    = ws + OFF_DINV;
  float* svec    = ws + OFF_S;
  float* pvec    = ws + OFF_P;
  float* rvec    = ws + OFF_R;
  float* wpart   = ws + OFF_WP;
  float* out = (float*)d_out;

  void* args[] = {(void*)&Xr, (void*)&Xi, (void*)&adj, (void*)&weight, (void*)&bias,
                  (void*)&rowsum, (void*)&colpart, (void*)&dinv, (void*)&pvec,
                  (void*)&rvec, (void*)&wpart, (void*)&out};
  hipError_t err = hipLaunchCooperativeKernel((const void*)k_all, dim3(512), dim3(256),
                                              args, 0, stream);
  if (err != hipSuccess) {
    // R8-proven fallback (53.4 us)
    fb_sums<<<dim3(NB, 64), 512, 0, stream>>>(adj, rowsum, colpart, out);
    fb_prep<<<dim3(NB*NN/256), 256, 0, stream>>>(Xr, Xi, weight, rowsum, colpart,
                                                 dinv, svec, pvec, rvec);
    fb_pass<0><<<dim3(NB, NN/64, 4), 512, 0, stream>>>(adj, dinv, rvec, wpart, svec, bias, out);
    fb_pass<1><<<dim3(NB, NN/64, 4), 512, 0, stream>>>(adj, dinv, pvec, wpart, svec, bias, out);
  }
}

// Round 17
// 244.641 us; speedup vs baseline: 1.4635x; 1.4635x over previous
//
#include <hip/hip_runtime.h>
#include <cstddef>

#define NB 8
#define NN 1024
#define NF 32
#define NIDX 4
#define NBLK 512u

// ---- ws layout (float offsets), shared by coop + fallback paths ----
#define OFF_ROW   0u
#define OFF_COLP  8192u          // [64][8192]
#define OFF_DINV  532480u
#define OFF_S     540672u        // fallback svec [8192][8]
#define OFF_P     606208u
#define OFF_R     671744u
#define OFF_WP    737280u        // coop: [2][65536]; fallback: [4][65536]
#define OFF_BAR   868352u        // 2 uints: arrival counter, generation

#if __has_builtin(__builtin_amdgcn_sinf)
#define FSIN(x) __builtin_amdgcn_sinf(x)   // sin(2*pi*x), |x|<0.5 here
#define FCOS(x) __builtin_amdgcn_cosf(x)
#else
#define FSIN(x) __sinf((x) * 6.283185307179586f)
#define FCOS(x) __cosf((x) * 6.283185307179586f)
#endif

#define TRIG6(dd, csv, snv)                                          \
  float s4 = FSIN(0.25f*(dd)), c4w = FCOS(0.25f*(dd));               \
  float s3 = FSIN((1.f/3.f)*(dd)), c3 = FCOS((1.f/3.f)*(dd));        \
  float s5 = FSIN(0.2f*(dd)), c5 = FCOS(0.2f*(dd));                  \
  float c2 = 1.f - 2.f*s4*s4, s2 = 2.f*s4*c4w;                       \
  csv[0]=c2; csv[1]=c3; csv[2]=c4w; csv[3]=c5;                       \
  snv[0]=s2; snv[1]=s3; snv[2]=s4; snv[3]=s5;

// 8x8 in-wave transpose-reduce (R4/R11-verified)
#define TREDUCE(accr, acci, red, w, lane, b1, b2, b4)                \
  _Pragma("unroll")                                                  \
  for (int s = 0; s < 8; ++s) {                                      \
    float v0 = accr[s][0], v1 = acci[s][0], v2 = accr[s][1], v3 = acci[s][1]; \
    float v4 = accr[s][2], v5 = acci[s][2], v6 = accr[s][3], v7 = acci[s][3]; \
    float k0 = b1 ? v1 : v0, s0 = b1 ? v0 : v1;                      \
    float k1 = b1 ? v3 : v2, s1 = b1 ? v2 : v3;                      \
    float k2 = b1 ? v5 : v4, s2_ = b1 ? v4 : v5;                     \
    float k3 = b1 ? v7 : v6, s3_ = b1 ? v6 : v7;                     \
    v0 = k0 + __shfl_xor(s0, 1);                                     \
    v1 = k1 + __shfl_xor(s1, 1);                                     \
    v2 = k2 + __shfl_xor(s2_, 1);                                    \
    v3 = k3 + __shfl_xor(s3_, 1);                                    \
    k0 = b2 ? v1 : v0; s0 = b2 ? v0 : v1;                            \
    k1 = b2 ? v3 : v2; s1 = b2 ? v2 : v3;                            \
    v0 = k0 + __shfl_xor(s0, 2);                                     \
    v1 = k1 + __shfl_xor(s1, 2);                                     \
    k0 = b4 ? v1 : v0; s0 = b4 ? v0 : v1;                            \
    v0 = k0 + __shfl_xor(s0, 4);                                     \
    red[w][s*72 + (lane & 7)*9 + (lane >> 3)] = v0;                  \
  }

// Fast device-scope grid barrier (cg::grid.sync measured ~110us each - R14).
// 1 lane/block arrives via device-scope atomicAdd, spins on generation word.
// Volatile loads on gfx940+ emit sc0/sc1 (bypass L1+L2) -> cross-XCD visible.
// BOUNDED spin (~7ms max): a malfunction produces a wrong result (visible
// absmax failure), never a GPU hang.
__device__ __forceinline__ void gbar(unsigned* cnt, volatile unsigned* gen) {
  __syncthreads();
  if (threadIdx.x == 0) {
    __threadfence();                       // release prior writes
    unsigned g = *gen;
    if (atomicAdd(cnt, 1u) == NBLK - 1u) {
      atomicExch(cnt, 0u);                 // reset before release
      __threadfence();
      atomicAdd((unsigned*)gen, 1u);       // release waiters
    } else {
      for (int spin = 0; *gen == g && spin < (1 << 17); ++spin)
        __builtin_amdgcn_s_sleep(2);
    }
    __threadfence();                       // acquire
  }
  __syncthreads();
}

__global__ void k_init(unsigned* bar) { bar[0] = 0u; bar[1] = 0u; }

// ================= single cooperative dispatch =================
// 512 blocks x 256 thr; bid%8 == batch b in EVERY phase (XCD-pinned).
// A: row+col sums  B: dinv+contractions, out=s+bias  C: wpart=halfM(rvec)
// D: out += halfM(dinv*(p+wpart0+wpart1))
__global__ __launch_bounds__(256, 4) void k_all(
    const float* __restrict__ Xr, const float* __restrict__ Xi,
    const float* __restrict__ adj, const float* __restrict__ weight,
    const float* __restrict__ bias,
    float* __restrict__ rowsum, float* __restrict__ colpart,
    float* __restrict__ dinv, float* __restrict__ pvec, float* __restrict__ rvec,
    float* __restrict__ wpart, float* __restrict__ out, unsigned* bar) {
  __shared__ union U {
    float cacc[4][NN];                                             // A: 16 KB
    struct { float Tjs[64][33]; float vlds[512][8]; float red[4][576]; } p;  // C/D: 33.6 KB
  } smu;
  int bid = blockIdx.x;
  int t = threadIdx.x, lane = t & 63, w = t >> 6;
  int wu = __builtin_amdgcn_readfirstlane(w);
  int b = bid & 7;
  unsigned* cnt = bar;
  volatile unsigned* gen = bar + 1;

  // ---------------- Phase A ----------------
  {
    int strip = bid >> 3;                       // 0..63, 16 rows each
    float colreg[16];
    #pragma unroll
    for (int i = 0; i < 16; ++i) colreg[i] = 0.f;
    int r0 = strip*16 + w*4;
    #pragma unroll
    for (int rr = 0; rr < 4; ++rr) {
      const float4* row4 = reinterpret_cast<const float4*>(adj + ((size_t)b*NN + r0 + rr)*NN);
      float rs = 0.f;
      #pragma unroll
      for (int cq = 0; cq < 4; ++cq) {
        float4 v = row4[cq*64 + lane];
        colreg[cq*4+0] += v.x; colreg[cq*4+1] += v.y;
        colreg[cq*4+2] += v.z; colreg[cq*4+3] += v.w;
        rs += (v.x + v.y) + (v.z + v.w);
      }
      #pragma unroll
      for (int o = 32; o > 0; o >>= 1) rs += __shfl_xor(rs, o);
      if (lane == 0) rowsum[b*NN + r0 + rr] = rs;
    }
    #pragma unroll
    for (int cq = 0; cq < 4; ++cq)
      #pragma unroll
      for (int x = 0; x < 4; ++x) smu.cacc[w][cq*256 + lane*4 + x] = colreg[cq*4+x];
    __syncthreads();
    for (int c = t; c < NN; c += 256) {
      float s = smu.cacc[0][c] + smu.cacc[1][c] + smu.cacc[2][c] + smu.cacc[3][c];
      colpart[(size_t)strip*(NB*NN) + b*NN + c] = s;
    }
  }
  gbar(cnt, gen);

  // ---------------- Phase B ----------------
  if (bid < 32) {
    int gid = bid*256 + t;
    float cs = 0.f;
    for (int k = 0; k < 64; ++k) cs += colpart[(size_t)k*(NB*NN) + gid];
    float D = 0.5f*(rowsum[gid] + cs);
    float di = (D > 0.f) ? (1.0f / sqrtf(D)) : 0.f;
    dinv[gid] = di;
    const float* xr = Xr + (size_t)gid*NF;
    const float* xi = Xi + (size_t)gid*NF;
    float acc[NIDX][3][2];
    #pragma unroll
    for (int x = 0; x < NIDX; ++x)
      #pragma unroll
      for (int v = 0; v < 3; ++v) { acc[x][v][0] = 0.f; acc[x][v][1] = 0.f; }
    for (int f = 0; f < NF; ++f) {
      float xrf = xr[f], xif = xi[f];
      #pragma unroll
      for (int x = 0; x < NIDX; ++x) {
        float w0 = weight[x*96 + f], w1 = weight[x*96 + 32 + f], w2 = weight[x*96 + 64 + f];
        float av = w0 + w2, bv = w1 + 2.f*w2, cv = -2.f*w2;
        acc[x][0][0] += av*xrf; acc[x][0][1] += av*xif;
        acc[x][1][0] += bv*xrf; acc[x][1][1] += bv*xif;
        acc[x][2][0] += cv*xrf; acc[x][2][1] += cv*xif;
      }
    }
    #pragma unroll
    for (int x = 0; x < NIDX; ++x) {
      size_t o = (size_t)gid*8 + x*2;
      pvec[o] = acc[x][1][0];      pvec[o+1] = acc[x][1][1];
      rvec[o] = di*acc[x][2][0];   rvec[o+1] = di*acc[x][2][1];
      out[gid*4 + x]         = acc[x][0][0] + bias[x];   // real
      out[32768 + gid*4 + x] = acc[x][0][1];             // imag
    }
  }
  gbar(cnt, gen);

  // ---------------- Phases C, D ----------------
  int it = (bid >> 3) & 31, zc = bid >> 8;    // 32-row i-tile, 512-j chunk
  int i0 = it*32, j0base = zc*512;
  int ibase = i0 + wu*8;
  bool b1 = (lane & 1), b2 = (lane & 2), b4 = (lane & 4);

  #pragma unroll 1
  for (int phase = 0; phase < 2; ++phase) {
    if (phase == 1) {
      for (int e = t; e < 512*8; e += 256) {
        int jj = e >> 3, s = e & 7;
        size_t o = ((size_t)b*NN + j0base + jj)*8 + s;
        float v = pvec[o] + wpart[o] + wpart[65536 + o];
        smu.p.vlds[jj][s] = v * dinv[b*NN + j0base + jj];
      }
    }
    float accr[8][NIDX], acci[8][NIDX];
    #pragma unroll
    for (int s = 0; s < 8; ++s)
      #pragma unroll
      for (int x = 0; x < NIDX; ++x) { accr[s][x] = 0.f; acci[s][x] = 0.f; }

    for (int jt = 0; jt < 8; ++jt) {
      int j0 = j0base + jt*64;
      __syncthreads();
      #pragma unroll
      for (int m = 0; m < 2; ++m) {
        int e4 = t + 256*m;                    // 512 float4 = 64j x 32i tile
        int jj = e4 >> 3, i4 = (e4 & 7) << 2;
        float4 vv = *reinterpret_cast<const float4*>(adj + ((size_t)b*NN + j0 + jj)*NN + i0 + i4);
        float* dst = &smu.p.Tjs[jj][i4];
        dst[0] = vv.x; dst[1] = vv.y; dst[2] = vv.z; dst[3] = vv.w;
      }
      float vr[NIDX], vi[NIDX];
      if (phase == 0) {
        const float4* vp = reinterpret_cast<const float4*>(rvec + ((size_t)b*NN + j0 + lane)*8);
        float4 v0 = vp[0], v1 = vp[1];
        vr[0]=v0.x; vi[0]=v0.y; vr[1]=v0.z; vi[1]=v0.w;
        vr[2]=v1.x; vi[2]=v1.y; vr[3]=v1.z; vi[3]=v1.w;
      } else {
        const float4* vp = reinterpret_cast<const float4*>(&smu.p.vlds[jt*64 + lane][0]);
        float4 v0 = vp[0], v1 = vp[1];
        vr[0]=v0.x; vi[0]=v0.y; vr[1]=v0.z; vi[1]=v0.w;
        vr[2]=v1.x; vi[2]=v1.y; vr[3]=v1.z; vi[3]=v1.w;
      }
      __syncthreads();
      const float* arb = adj + ((size_t)b*NN + ibase)*NN + j0 + lane;
      #pragma unroll
      for (int s = 0; s < 8; ++s) {
        float ar = arb[(size_t)s*NN];          // adj[i][j], coalesced
        float ac = smu.p.Tjs[lane][wu*8 + s];  // adj[j][i], 2-way free
        float dd = ar - ac, sm = ar + ac;
        float csv[NIDX], snv[NIDX];
        TRIG6(dd, csv, snv)
        #pragma unroll
        for (int x = 0; x < NIDX; ++x) {
          float A = sm*csv[x], B = sm*snv[x];
          accr[s][x] += A*vr[x] - B*vi[x];
          acci[s][x] += A*vi[x] + B*vr[x];
        }
      }
    }
    TREDUCE(accr, acci, smu.p.red, w, lane, b1, b2, b4)
    __syncthreads();
    {
      int row = lane >> 3, slot = lane & 7;    // wave-local 8 rows x 8 slots
      float sum = 0.f;
      #pragma unroll
      for (int g = 0; g < 8; ++g) sum += smu.p.red[w][row*72 + slot*9 + g];
      int gi = b*NN + ibase + row;
      float val = sum * 0.5f * dinv[gi];
      if (phase == 0) wpart[(size_t)zc*65536 + (size_t)gi*8 + slot] = val;
      else atomicAdd(&out[(slot & 1)*32768 + gi*4 + (slot >> 1)], val);
    }
    if (phase == 0) gbar(cnt, gen);
  }
}

// ================= fallback: R8-proven 4-dispatch path (53.4 us) =================
__global__ __launch_bounds__(512) void fb_sums(const float* __restrict__ adj,
                                               float* __restrict__ rowsum,
                                               float* __restrict__ colpart,
                                               float* __restrict__ out) {
  int b = blockIdx.x, strip = blockIdx.y;
  int t = threadIdx.x, lane = t & 63, w = t >> 6;
  { int zid = blockIdx.x*64 + blockIdx.y;
    if (t < 128) out[zid*128 + t] = 0.f; }
  float colreg[16];
  #pragma unroll
  for (int i = 0; i < 16; ++i) colreg[i] = 0.f;
  int r0 = strip*16 + w*2;
  #pragma unroll
  for (int rr = 0; rr < 2; ++rr) {
    const float4* row4 = reinterpret_cast<const float4*>(adj + ((size_t)b*NN + r0 + rr)*NN);
    float rs = 0.f;
    #pragma unroll
    for (int cq = 0; cq < 4; ++cq) {
      float4 v = row4[cq*64 + lane];
      colreg[cq*4+0] += v.x; colreg[cq*4+1] += v.y;
      colreg[cq*4+2] += v.z; colreg[cq*4+3] += v.w;
      rs += (v.x + v.y) + (v.z + v.w);
    }
    #pragma unroll
    for (int o = 32; o > 0; o >>= 1) rs += __shfl_xor(rs, o);
    if (lane == 0) rowsum[b*NN + r0 + rr] = rs;
  }
  __shared__ float cacc[8][NN];
  #pragma unroll
  for (int cq = 0; cq < 4; ++cq)
    #pragma unroll
    for (int x = 0; x < 4; ++x) cacc[w][cq*256 + lane*4 + x] = colreg[cq*4+x];
  __syncthreads();
  for (int c = t; c < NN; c += 512) {
    float s = 0.f;
    #pragma unroll
    for (int ww = 0; ww < 8; ++ww) s += cacc[ww][c];
    colpart[(size_t)strip*(NB*NN) + b*NN + c] = s;
  }
}

__global__ __launch_bounds__(256) void fb_prep(const float* __restrict__ Xr, const float* __restrict__ Xi,
                       const float* __restrict__ weight,
                       const float* __restrict__ rowsum, const float* __restrict__ colpart,
                       float* __restrict__ dinv,
                       float* __restrict__ svec, float* __restrict__ pvec, float* __restrict__ rvec) {
  __shared__ float wsm[NIDX*3*NF];
  int t = threadIdx.x;
  for (int e = t; e < NIDX*3*NF; e += 256) wsm[e] = weight[e];
  __syncthreads();
  int gid = blockIdx.x*256 + t;
  float cs = 0.f;
  for (int k = 0; k < 64; ++k) cs += colpart[(size_t)k*(NB*NN) + gid];
  float D = 0.5f*(rowsum[gid] + cs);
  float di = (D > 0.f) ? (1.0f / sqrtf(D)) : 0.f;
  dinv[gid] = di;
  const float* xr = Xr + (size_t)gid*NF;
  const float* xi = Xi + (size_t)gid*NF;
  float acc[NIDX][3][2];
  #pragma unroll
  for (int x = 0; x < NIDX; ++x)
    #pragma unroll
    for (int v = 0; v < 3; ++v) { acc[x][v][0] = 0.f; acc[x][v][1] = 0.f; }
  for (int f = 0; f < NF; ++f) {
    float xrf = xr[f], xif = xi[f];
    #pragma unroll
    for (int x = 0; x < NIDX; ++x) {
      float w0 = wsm[x*96 + f], w1 = wsm[x*96 + 32 + f], w2 = wsm[x*96 + 64 + f];
      float av = w0 + w2, bv = w1 + 2.f*w2, cv = -2.f*w2;
      acc[x][0][0] += av*xrf; acc[x][0][1] += av*xif;
      acc[x][1][0] += bv*xrf; acc[x][1][1] += bv*xif;
      acc[x][2][0] += cv*xrf; acc[x][2][1] += cv*xif;
    }
  }
  #pragma unroll
  for (int x = 0; x < NIDX; ++x) {
    size_t o = (size_t)gid*8 + x*2;
    svec[o] = acc[x][0][0];      svec[o+1] = acc[x][0][1];
    pvec[o] = acc[x][1][0];      pvec[o+1] = acc[x][1][1];
    rvec[o] = di*acc[x][2][0];   rvec[o+1] = di*acc[x][2][1];
  }
}

template<int MODE>
__global__ __launch_bounds__(512, 4) void fb_pass(const float* __restrict__ adj,
                                                  const float* __restrict__ dinv,
                                                  const float* __restrict__ vin,
                                                  float* __restrict__ wpart,
                                                  const float* __restrict__ svec,
                                                  const float* __restrict__ bias,
                                                  float* __restrict__ out) {
  __shared__ float Tjs[64][65];
  __shared__ float vlds[256][8];
  __shared__ float red[8][8*72];
  int b = blockIdx.x, i0 = blockIdx.y*64, zc = blockIdx.z;
  int j0base = zc*256;
  int t = threadIdx.x, lane = t & 63;
  int w = t >> 6;
  int wu = __builtin_amdgcn_readfirstlane(w);

  if constexpr (MODE == 1) {
    for (int e = t; e < 256*8; e += 512) {
      int jj = e >> 3, s = e & 7;
      size_t o = ((size_t)b*NN + j0base + jj)*8 + s;
      float v = vin[o];
      #pragma unroll
      for (int c = 0; c < 4; ++c) v += wpart[(size_t)c*65536 + o];
      vlds[jj][s] = v * dinv[b*NN + j0base + jj];
    }
  }
  float accr[8][NIDX], acci[8][NIDX];
  #pragma unroll
  for (int s = 0; s < 8; ++s)
    #pragma unroll
    for (int x = 0; x < NIDX; ++x) { accr[s][x] = 0.f; acci[s][x] = 0.f; }

  for (int jt = 0; jt < 4; ++jt) {
    int j0 = j0base + jt*64;
    __syncthreads();
    #pragma unroll
    for (int m = 0; m < 2; ++m) {
      int e4 = t + 512*m;
      int jj = e4 >> 4, i4 = (e4 & 15) << 2;
      float4 vv = *reinterpret_cast<const float4*>(adj + ((size_t)b*NN + j0 + jj)*NN + i0 + i4);
      float* dst = &Tjs[jj][i4];
      dst[0] = vv.x; dst[1] = vv.y; dst[2] = vv.z; dst[3] = vv.w;
    }
    float vr[NIDX], vi[NIDX];
    if constexpr (MODE == 0) {
      const float4* vb = reinterpret_cast<const float4*>(vin + ((size_t)b*NN + j0 + lane)*8);
      float4 a = vb[0], c = vb[1];
      vr[0]=a.x; vi[0]=a.y; vr[1]=a.z; vi[1]=a.w;
      vr[2]=c.x; vi[2]=c.y; vr[3]=c.z; vi[3]=c.w;
    } else {
      const float4* vb = reinterpret_cast<const float4*>(&vlds[jt*64 + lane][0]);
      float4 a = vb[0], c = vb[1];
      vr[0]=a.x; vi[0]=a.y; vr[1]=a.z; vi[1]=a.w;
      vr[2]=c.x; vi[2]=c.y; vr[3]=c.z; vi[3]=c.w;
    }
    __syncthreads();
    const float* arbase = adj + ((size_t)b*NN + i0 + wu*8)*NN + j0 + lane;
    #pragma unroll
    for (int s = 0; s < 8; ++s) {
      float ar = arbase[(size_t)s*NN];
      float ac = Tjs[lane][wu*8 + s];
      float dd = ar - ac, sm = ar + ac;
      float csv[NIDX], snv[NIDX];
      TRIG6(dd, csv, snv)
      #pragma unroll
      for (int x = 0; x < NIDX; ++x) {
        float A = sm*csv[x], B = sm*snv[x];
        accr[s][x] += A*vr[x] - B*vi[x];
        acci[s][x] += A*vi[x] + B*vr[x];
      }
    }
  }
  bool b1 = (lane & 1), b2 = (lane & 2), b4 = (lane & 4);
  TREDUCE(accr, acci, red, w, lane, b1, b2, b4)
  __syncthreads();
  {
    int iloc = w*8 + (lane >> 3), slot = lane & 7;
    float sum = 0.f;
    #pragma unroll
    for (int g = 0; g < 8; ++g) sum += red[w][(lane >> 3)*72 + slot*9 + g];
    int i = i0 + iloc;
    float val = sum * 0.5f * dinv[b*NN + i];
    if constexpr (MODE == 0) {
      wpart[(size_t)zc*65536 + ((size_t)b*NN + i)*8 + slot] = val;
    } else {
      if (zc == 0) {
        val += svec[((size_t)b*NN + i)*8 + slot];
        if ((slot & 1) == 0) val += bias[slot >> 1];
      }
      atomicAdd(&out[(slot & 1)*32768 + b*4096 + i*4 + (slot >> 1)], val);
    }
  }
}

extern "C" void kernel_launch(void* const* d_in, const int* in_sizes, int n_in,
                              void* d_out, int out_size, void* d_ws, size_t ws_size,
                              hipStream_t stream) {
  (void)in_sizes; (void)n_in; (void)out_size; (void)ws_size;
  const float* Xr     = (const float*)d_in[0];
  const float* Xi     = (const float*)d_in[1];
  const float* adj    = (const float*)d_in[2];
  const float* weight = (const float*)d_in[3];
  const float* bias   = (const float*)d_in[4];
  float* ws = (float*)d_ws;
  float* rowsum  = ws + OFF_ROW;
  float* colpart = ws + OFF_COLP;
  float* dinv    = ws + OFF_DINV;
  float* svec    = ws + OFF_S;
  float* pvec    = ws + OFF_P;
  float* rvec    = ws + OFF_R;
  float* wpart   = ws + OFF_WP;
  unsigned* bar  = (unsigned*)(ws + OFF_BAR);
  float* out = (float*)d_out;

  k_init<<<dim3(1), 64, 0, stream>>>(bar);
  void* args[] = {(void*)&Xr, (void*)&Xi, (void*)&adj, (void*)&weight, (void*)&bias,
                  (void*)&rowsum, (void*)&colpart, (void*)&dinv, (void*)&pvec,
                  (void*)&rvec, (void*)&wpart, (void*)&out, (void*)&bar};
  hipError_t err = hipLaunchCooperativeKernel((const void*)k_all, dim3(512), dim3(256),
                                              args, 0, stream);
  if (err != hipSuccess) {
    // R8-proven fallback (53.4 us)
    fb_sums<<<dim3(NB, 64), 512, 0, stream>>>(adj, rowsum, colpart, out);
    fb_prep<<<dim3(NB*NN/256), 256, 0, stream>>>(Xr, Xi, weight, rowsum, colpart,
                                                 dinv, svec, pvec, rvec);
    fb_pass<0><<<dim3(NB, NN/64, 4), 512, 0, stream>>>(adj, dinv, rvec, wpart, svec, bias, out);
    fb_pass<1><<<dim3(NB, NN/64, 4), 512, 0, stream>>>(adj, dinv, pvec, wpart, svec, bias, out);
  }
}

// Round 19
// 66.453 us; speedup vs baseline: 5.3879x; 3.6814x over previous
//
#include <hip/hip_runtime.h>
#include <hip/hip_fp16.h>
#include <cstddef>

#define NB 8
#define NN 1024
#define NF 32
#define NIDX 4
#define NTILE 16
#define NPAIR 136        // NTILE*(NTILE+1)/2
#define JC 4             // j-chunks per pass

// ---- ws layout (float offsets) ----
#define OFF_D     0u           // Dpart[16][8192] plain-store partials
#define OFF_DINV  131072u
#define OFF_SMDD  139264u      // u32[8][1024][1024] packed (half sm, half dd)
#define OFF_P     8527872u
#define OFF_R     8593408u
#define OFF_WT    8658944u
#define OFF_WP    8724480u     // [JC][65536]

#if __has_builtin(__builtin_amdgcn_sinf)
#define FSIN(x) __builtin_amdgcn_sinf(x)   // sin(2*pi*x), |x|<0.5 here
#define FCOS(x) __builtin_amdgcn_cosf(x)
#else
#define FSIN(x) __sinf((x) * 6.283185307179586f)
#define FCOS(x) __cosf((x) * 6.283185307179586f)
#endif

#define TRIG6(dd, csv, snv)                                          \
  float s4 = FSIN(0.25f*(dd)), c4w = FCOS(0.25f*(dd));               \
  float s3 = FSIN((1.f/3.f)*(dd)), c3 = FCOS((1.f/3.f)*(dd));        \
  float s5 = FSIN(0.2f*(dd)), c5 = FCOS(0.2f*(dd));                  \
  float c2 = 1.f - 2.f*s4*s4, s2 = 2.f*s4*c4w;                       \
  csv[0]=c2; csv[1]=c3; csv[2]=c4w; csv[3]=c5;                       \
  snv[0]=s2; snv[1]=s3; snv[2]=s4; snv[3]=s5;

// 8x8 in-wave transpose-reduce (R4/R10/R11-verified)
#define TREDUCE(accr, acci, red, w, lane, b1, b2, b4)                \
  _Pragma("unroll")                                                  \
  for (int s = 0; s < 8; ++s) {                                      \
    float v0 = accr[s][0], v1 = acci[s][0], v2 = accr[s][1], v3 = acci[s][1]; \
    float v4 = accr[s][2], v5 = acci[s][2], v6 = accr[s][3], v7 = acci[s][3]; \
    float k0 = b1 ? v1 : v0, s0 = b1 ? v0 : v1;                      \
    float k1 = b1 ? v3 : v2, s1 = b1 ? v2 : v3;                      \
    float k2 = b1 ? v5 : v4, s2_ = b1 ? v4 : v5;                     \
    float k3 = b1 ? v7 : v6, s3_ = b1 ? v6 : v7;                     \
    v0 = k0 + __shfl_xor(s0, 1);                                     \
    v1 = k1 + __shfl_xor(s1, 1);                                     \
    v2 = k2 + __shfl_xor(s2_, 1);                                    \
    v3 = k3 + __shfl_xor(s3_, 1);                                    \
    k0 = b2 ? v1 : v0; s0 = b2 ? v0 : v1;                            \
    k1 = b2 ? v3 : v2; s1 = b2 ? v2 : v3;                            \
    v0 = k0 + __shfl_xor(s0, 2);                                     \
    v1 = k1 + __shfl_xor(s1, 2);                                     \
    k0 = b4 ? v1 : v0; s0 = b4 ? v0 : v1;                            \
    v0 = k0 + __shfl_xor(s0, 4);                                     \
    red[w][s*72 + (lane & 7)*9 + (lane >> 3)] = v0;                  \
  }

// Pack kernel: per (b, tile-pair ti<=tj) block, one read of both tile
// orientations -> smdd[i][j] = half2(a_ij + a_ji, a_ij - a_ji) for BOTH
// orientations (dd negated), plus per-tile row-sum partials of sm
// (Dpart, plain stores - each slot written exactly once, no zeroing).
__global__ __launch_bounds__(256, 4) void k_pack(const float* __restrict__ adj,
                                                 unsigned* __restrict__ smdd,
                                                 float* __restrict__ Dpart) {
  __shared__ float As[64*65];
  __shared__ float Bs[64*65];
  int b = blockIdx.x;
  int pid = blockIdx.y;
  int ti = 0, rem = pid;
  while (rem >= NTILE - ti) { rem -= NTILE - ti; ++ti; }
  int tj = ti + rem;
  bool diag = (ti == tj);
  int t = threadIdx.x, lane = t & 63, w = t >> 6;

  #pragma unroll
  for (int m = 0; m < 4; ++m) {
    int e4 = t + 256*m;                    // 1024 float4 = 64x64 tile
    int row = e4 >> 4, c4 = (e4 & 15) << 2;
    float4 va = *reinterpret_cast<const float4*>(adj + ((size_t)b*NN + ti*64 + row)*NN + tj*64 + c4);
    float* da = &As[row*65 + c4];
    da[0] = va.x; da[1] = va.y; da[2] = va.z; da[3] = va.w;
    if (!diag) {
      float4 vb = *reinterpret_cast<const float4*>(adj + ((size_t)b*NN + tj*64 + row)*NN + ti*64 + c4);
      float* db = &Bs[row*65 + c4];
      db[0] = vb.x; db[1] = vb.y; db[2] = vb.z; db[3] = vb.w;
    }
  }
  __syncthreads();

  const float* Bp = diag ? As : Bs;
  // out1: rows of tile ti, cols of tile tj
  #pragma unroll
  for (int m = 0; m < 16; ++m) {
    int r = w + 4*m, c = lane;            // e = t + 256m -> row w+4m, col lane
    float a  = As[r*65 + c];
    float bt = Bp[c*65 + r];
    float sm = a + bt, dd = a - bt;
    __half2 h = __floats2half2_rn(sm, dd);
    smdd[((size_t)b*NN + ti*64 + r)*NN + tj*64 + c] = *reinterpret_cast<unsigned*>(&h);
    float rp = sm;
    #pragma unroll
    for (int o = 32; o > 0; o >>= 1) rp += __shfl_xor(rp, o);
    if (lane == 0) Dpart[(size_t)tj*(NB*NN) + b*NN + ti*64 + r] = 0.5f*rp;
  }
  // out2: rows of tile tj, cols of tile ti (skip on diagonal)
  if (!diag) {
    #pragma unroll
    for (int m = 0; m < 16; ++m) {
      int r = w + 4*m, c = lane;
      float a  = Bs[r*65 + c];            // adj[tj+r][ti+c]
      float bt = As[c*65 + r];            // adj[ti+c][tj+r]
      float sm = a + bt, dd = a - bt;
      __half2 h = __floats2half2_rn(sm, dd);
      smdd[((size_t)b*NN + tj*64 + r)*NN + ti*64 + c] = *reinterpret_cast<unsigned*>(&h);
      float rp = sm;
      #pragma unroll
      for (int o = 32; o > 0; o >>= 1) rp += __shfl_xor(rp, o);
      if (lane == 0) Dpart[(size_t)ti*(NB*NN) + b*NN + tj*64 + r] = 0.5f*rp;
    }
  }
}

// dinv + feature contractions; pre-initializes out = s + bias.
__global__ __launch_bounds__(256) void k_prep(const float* __restrict__ Xr, const float* __restrict__ Xi,
                       const float* __restrict__ weight,
                       const float* __restrict__ Dpart, const float* __restrict__ bias,
                       float* __restrict__ dinv,
                       float* __restrict__ pvec, float* __restrict__ rvec,
                       float* __restrict__ out) {
  __shared__ float wsm[NIDX*3*NF];
  int t = threadIdx.x;
  for (int e = t; e < NIDX*3*NF; e += 256) wsm[e] = weight[e];
  __syncthreads();
  int gid = blockIdx.x*256 + t;
  float D = 0.f;
  #pragma unroll
  for (int k = 0; k < NTILE; ++k) D += Dpart[(size_t)k*(NB*NN) + gid];
  float di = (D > 0.f) ? (1.0f / sqrtf(D)) : 0.f;
  dinv[gid] = di;
  const float* xr = Xr + (size_t)gid*NF;
  const float* xi = Xi + (size_t)gid*NF;
  float acc[NIDX][3][2];
  #pragma unroll
  for (int x = 0; x < NIDX; ++x)
    #pragma unroll
    for (int v = 0; v < 3; ++v) { acc[x][v][0] = 0.f; acc[x][v][1] = 0.f; }
  for (int f = 0; f < NF; ++f) {
    float xrf = xr[f], xif = xi[f];
    #pragma unroll
    for (int x = 0; x < NIDX; ++x) {
      float w0 = wsm[x*96 + f], w1 = wsm[x*96 + 32 + f], w2 = wsm[x*96 + 64 + f];
      float av = w0 + w2, bv = w1 + 2.f*w2, cv = -2.f*w2;
      acc[x][0][0] += av*xrf; acc[x][0][1] += av*xif;
      acc[x][1][0] += bv*xrf; acc[x][1][1] += bv*xif;
      acc[x][2][0] += cv*xrf; acc[x][2][1] += cv*xif;
    }
  }
  #pragma unroll
  for (int x = 0; x < NIDX; ++x) {
    size_t o = (size_t)gid*8 + x*2;
    pvec[o] = acc[x][1][0];      pvec[o+1] = acc[x][1][1];
    rvec[o] = di*acc[x][2][0];   rvec[o+1] = di*acc[x][2][1];
    out[gid*4 + x]         = acc[x][0][0] + bias[x];   // real
    out[32768 + gid*4 + x] = acc[x][0][1];             // imag
  }
}

// wtot = dinv * (pvec + sum_c wpart[c])
__global__ void k_mid(const float* __restrict__ dinv, const float* __restrict__ pvec,
                      const float* __restrict__ wpart, float* __restrict__ wtot) {
  int o = blockIdx.x*256 + threadIdx.x;   // 65536
  float v = pvec[o];
  #pragma unroll
  for (int c = 0; c < JC; ++c) v += wpart[(size_t)c*65536 + o];
  wtot[o] = v * dinv[o >> 3];
}

// Barrier-free streaming M-application over packed smdd.
// Block = 4 waves / 32 i-rows; wave owns 8 rows; lanes on j. Per jt (64 j's):
// v (float4 x2, L2) + 8 coalesced u32 smdd loads. No LDS tiles, no staging.
// MODE 0: vin=rvec -> plain-store wpart[zc]. MODE 1: vin=wtot -> atomicAdd out.
template<int MODE>
__global__ __launch_bounds__(256, 4) void k_pass(const unsigned* __restrict__ smdd,
                                                 const float* __restrict__ dinv,
                                                 const float* __restrict__ vin,
                                                 float* __restrict__ outp) {
  __shared__ float red[4][8*72];
  int b = blockIdx.x, i0 = blockIdx.y*32, zc = blockIdx.z;
  int t = threadIdx.x, lane = t & 63, w = t >> 6;
  int wu = __builtin_amdgcn_readfirstlane(w);
  int ibase = i0 + wu*8;
  float accr[8][NIDX], acci[8][NIDX];
  #pragma unroll
  for (int s = 0; s < 8; ++s)
    #pragma unroll
    for (int x = 0; x < NIDX; ++x) { accr[s][x] = 0.f; acci[s][x] = 0.f; }

  for (int jt = 0; jt < (NN/JC)/64; ++jt) {
    int jg = zc*(NN/JC) + jt*64 + lane;
    const float4* vp = reinterpret_cast<const float4*>(vin + ((size_t)b*NN + jg)*8);
    float4 va = vp[0], vb = vp[1];
    float vr[NIDX] = {va.x, va.z, vb.x, vb.z};
    float vi[NIDX] = {va.y, va.w, vb.y, vb.w};
    const unsigned* sp = smdd + ((size_t)b*NN + ibase)*NN + jg;
    #pragma unroll
    for (int s = 0; s < 8; ++s) {
      unsigned wrd = sp[(size_t)s*NN];                 // coalesced
      __half2 h = *reinterpret_cast<__half2*>(&wrd);
      float sm = __low2float(h), dd = __high2float(h);
      float csv[NIDX], snv[NIDX];
      TRIG6(dd, csv, snv)
      #pragma unroll
      for (int x = 0; x < NIDX; ++x) {
        float A = sm*csv[x], B = sm*snv[x];
        accr[s][x] += A*vr[x] - B*vi[x];
        acci[s][x] += A*vi[x] + B*vr[x];
      }
    }
  }

  bool b1 = (lane & 1), b2 = (lane & 2), b4 = (lane & 4);
  TREDUCE(accr, acci, red, w, lane, b1, b2, b4)
  __syncthreads();
  {
    int row = lane >> 3, slot = lane & 7;    // wave-local 8 rows x 8 slots
    float sum = 0.f;
    #pragma unroll
    for (int g = 0; g < 8; ++g) sum += red[w][row*72 + slot*9 + g];
    int gi = b*NN + ibase + row;
    float val = sum * 0.5f * dinv[gi];
    if constexpr (MODE == 0) outp[(size_t)zc*65536 + (size_t)gi*8 + slot] = val;
    else atomicAdd(&outp[(slot & 1)*32768 + gi*4 + (slot >> 1)], val);
  }
}

extern "C" void kernel_launch(void* const* d_in, const int* in_sizes, int n_in,
                              void* d_out, int out_size, void* d_ws, size_t ws_size,
                              hipStream_t stream) {
  (void)in_sizes; (void)n_in; (void)out_size; (void)ws_size;
  const float* Xr     = (const float*)d_in[0];
  const float* Xi     = (const float*)d_in[1];
  const float* adj    = (const float*)d_in[2];
  const float* weight = (const float*)d_in[3];
  const float* bias   = (const float*)d_in[4];
  float* ws = (float*)d_ws;
  float* Dpart   = ws + OFF_D;
  float* dinv    = ws + OFF_DINV;
  unsigned* smdd = (unsigned*)(ws + OFF_SMDD);
  float* pvec    = ws + OFF_P;
  float* rvec    = ws + OFF_R;
  float* wtot    = ws + OFF_WT;
  float* wpart   = ws + OFF_WP;
  float* out = (float*)d_out;

  k_pack<<<dim3(NB, NPAIR), 256, 0, stream>>>(adj, smdd, Dpart);
  k_prep<<<dim3(NB*NN/256), 256, 0, stream>>>(Xr, Xi, weight, Dpart, bias,
                                              dinv, pvec, rvec, out);
  k_pass<0><<<dim3(NB, NN/32, JC), 256, 0, stream>>>(smdd, dinv, rvec, wpart);
  k_mid<<<dim3(256), 256, 0, stream>>>(dinv, pvec, wpart, wtot);
  k_pass<1><<<dim3(NB, NN/32, JC), 256, 0, stream>>>(smdd, dinv, wtot, out);
}

// Round 20
// 58.173 us; speedup vs baseline: 6.1548x; 1.1423x over previous
//
#include <hip/hip_runtime.h>
#include <hip/hip_fp16.h>
#include <cstddef>

#define NB 8
#define NN 1024
#define NF 32
#define NIDX 4
#define JC 4             // j-chunks per pass

// ---- ws layout (float offsets) ----
#define OFF_ROW   0u          // rowsum [8192]
#define OFF_COLP  8192u       // colpart [64][8192]
#define OFF_DINV  532480u
#define OFF_R     540672u     // rvec [8192][8] (dinv_j prefolded)
#define OFF_WT    606208u     // wtot accumulator [8192][8] (init=pvec, pass0 adds w)
#define OFF_SMDD  671744u     // u32[8][1024][1024] packed half2(sm, dd)

#if __has_builtin(__builtin_amdgcn_sinf)
#define FSIN(x) __builtin_amdgcn_sinf(x)   // sin(2*pi*x), |x|<0.5 here
#define FCOS(x) __builtin_amdgcn_cosf(x)
#else
#define FSIN(x) __sinf((x) * 6.283185307179586f)
#define FCOS(x) __cosf((x) * 6.283185307179586f)
#endif

#define TRIG6(dd, csv, snv)                                          \
  float s4 = FSIN(0.25f*(dd)), c4w = FCOS(0.25f*(dd));               \
  float s3 = FSIN((1.f/3.f)*(dd)), c3 = FCOS((1.f/3.f)*(dd));        \
  float s5 = FSIN(0.2f*(dd)), c5 = FCOS(0.2f*(dd));                  \
  float c2 = 1.f - 2.f*s4*s4, s2 = 2.f*s4*c4w;                       \
  csv[0]=c2; csv[1]=c3; csv[2]=c4w; csv[3]=c5;                       \
  snv[0]=s2; snv[1]=s3; snv[2]=s4; snv[3]=s5;

// 8x8 in-wave transpose-reduce (R4/R10/R11/R19-verified)
#define TREDUCE(accr, acci, red, w, lane, b1, b2, b4)                \
  _Pragma("unroll")                                                  \
  for (int s = 0; s < 8; ++s) {                                      \
    float v0 = accr[s][0], v1 = acci[s][0], v2 = accr[s][1], v3 = acci[s][1]; \
    float v4 = accr[s][2], v5 = acci[s][2], v6 = accr[s][3], v7 = acci[s][3]; \
    float k0 = b1 ? v1 : v0, s0 = b1 ? v0 : v1;                      \
    float k1 = b1 ? v3 : v2, s1 = b1 ? v2 : v3;                      \
    float k2 = b1 ? v5 : v4, s2_ = b1 ? v4 : v5;                     \
    float k3 = b1 ? v7 : v6, s3_ = b1 ? v6 : v7;                     \
    v0 = k0 + __shfl_xor(s0, 1);                                     \
    v1 = k1 + __shfl_xor(s1, 1);                                     \
    v2 = k2 + __shfl_xor(s2_, 1);                                    \
    v3 = k3 + __shfl_xor(s3_, 1);                                    \
    k0 = b2 ? v1 : v0; s0 = b2 ? v0 : v1;                            \
    k1 = b2 ? v3 : v2; s1 = b2 ? v2 : v3;                            \
    v0 = k0 + __shfl_xor(s0, 2);                                     \
    v1 = k1 + __shfl_xor(s1, 2);                                     \
    k0 = b4 ? v1 : v0; s0 = b4 ? v0 : v1;                            \
    v0 = k0 + __shfl_xor(s0, 4);                                     \
    red[w][s*72 + (lane & 7)*9 + (lane >> 3)] = v0;                  \
  }

// Fused row+col sums of adj in one read (R8-proven). grid (NB,64).
__global__ __launch_bounds__(512) void k_sums(const float* __restrict__ adj,
                                              float* __restrict__ rowsum,
                                              float* __restrict__ colpart) {
  int b = blockIdx.x, strip = blockIdx.y;
  int t = threadIdx.x, lane = t & 63, w = t >> 6;
  float colreg[16];
  #pragma unroll
  for (int i = 0; i < 16; ++i) colreg[i] = 0.f;
  int r0 = strip*16 + w*2;
  #pragma unroll
  for (int rr = 0; rr < 2; ++rr) {
    const float4* row4 = reinterpret_cast<const float4*>(adj + ((size_t)b*NN + r0 + rr)*NN);
    float rs = 0.f;
    #pragma unroll
    for (int cq = 0; cq < 4; ++cq) {
      float4 v = row4[cq*64 + lane];
      colreg[cq*4+0] += v.x; colreg[cq*4+1] += v.y;
      colreg[cq*4+2] += v.z; colreg[cq*4+3] += v.w;
      rs += (v.x + v.y) + (v.z + v.w);
    }
    #pragma unroll
    for (int o = 32; o > 0; o >>= 1) rs += __shfl_xor(rs, o);
    if (lane == 0) rowsum[b*NN + r0 + rr] = rs;
  }
  __shared__ float cacc[8][NN];
  #pragma unroll
  for (int cq = 0; cq < 4; ++cq)
    #pragma unroll
    for (int x = 0; x < 4; ++x) cacc[w][cq*256 + lane*4 + x] = colreg[cq*4+x];
  __syncthreads();
  for (int c = t; c < NN; c += 512) {
    float s = 0.f;
    #pragma unroll
    for (int ww = 0; ww < 8; ++ww) s += cacc[ww][c];
    colpart[(size_t)strip*(NB*NN) + b*NN + c] = s;
  }
}

// dinv + feature contractions. Pre-initializes wtot := pvec and out := s+bias.
__global__ __launch_bounds__(256) void k_prep(const float* __restrict__ Xr, const float* __restrict__ Xi,
                       const float* __restrict__ weight,
                       const float* __restrict__ rowsum, const float* __restrict__ colpart,
                       const float* __restrict__ bias,
                       float* __restrict__ dinv, float* __restrict__ rvec,
                       float* __restrict__ wtot, float* __restrict__ out) {
  __shared__ float wsm[NIDX*3*NF];
  int t = threadIdx.x;
  for (int e = t; e < NIDX*3*NF; e += 256) wsm[e] = weight[e];
  __syncthreads();
  int gid = blockIdx.x*256 + t;
  float cs = 0.f;
  for (int k = 0; k < 64; ++k) cs += colpart[(size_t)k*(NB*NN) + gid];
  float D = 0.5f*(rowsum[gid] + cs);
  float di = (D > 0.f) ? (1.0f / sqrtf(D)) : 0.f;
  dinv[gid] = di;
  const float* xr = Xr + (size_t)gid*NF;
  const float* xi = Xi + (size_t)gid*NF;
  float acc[NIDX][3][2];
  #pragma unroll
  for (int x = 0; x < NIDX; ++x)
    #pragma unroll
    for (int v = 0; v < 3; ++v) { acc[x][v][0] = 0.f; acc[x][v][1] = 0.f; }
  for (int f = 0; f < NF; ++f) {
    float xrf = xr[f], xif = xi[f];
    #pragma unroll
    for (int x = 0; x < NIDX; ++x) {
      float w0 = wsm[x*96 + f], w1 = wsm[x*96 + 32 + f], w2 = wsm[x*96 + 64 + f];
      float av = w0 + w2, bv = w1 + 2.f*w2, cv = -2.f*w2;
      acc[x][0][0] += av*xrf; acc[x][0][1] += av*xif;
      acc[x][1][0] += bv*xrf; acc[x][1][1] += bv*xif;
      acc[x][2][0] += cv*xrf; acc[x][2][1] += cv*xif;
    }
  }
  #pragma unroll
  for (int x = 0; x < NIDX; ++x) {
    size_t o = (size_t)gid*8 + x*2;
    rvec[o] = di*acc[x][2][0];   rvec[o+1] = di*acc[x][2][1];
    wtot[o] = acc[x][1][0];      wtot[o+1] = acc[x][1][1];     // pvec
    out[gid*4 + x]         = acc[x][0][0] + bias[x];   // real
    out[32768 + gid*4 + x] = acc[x][0][1];             // imag
  }
}

// Pass 0 (R8-proven structure + smdd emission): w = halfM(rvec), atomicAdd into
// wtot (pre-init pvec). Also packs smdd[i][j] = half2(sm, dd) - free here since
// both adj orientations are in registers. grid (NB, 16, JC), 512 thr.
__global__ __launch_bounds__(512, 4) void k_pass0(const float* __restrict__ adj,
                                                  const float* __restrict__ dinv,
                                                  const float* __restrict__ rvec,
                                                  unsigned* __restrict__ smdd,
                                                  float* __restrict__ wtot) {
  __shared__ float Tjs[64][65];
  __shared__ float red[8][8*72];
  int b = blockIdx.x, i0 = blockIdx.y*64, zc = blockIdx.z;
  int j0base = zc*(NN/JC);
  int t = threadIdx.x, lane = t & 63;
  int w = t >> 6;
  int wu = __builtin_amdgcn_readfirstlane(w);

  float accr[8][NIDX], acci[8][NIDX];
  #pragma unroll
  for (int s = 0; s < 8; ++s)
    #pragma unroll
    for (int x = 0; x < NIDX; ++x) { accr[s][x] = 0.f; acci[s][x] = 0.f; }

  for (int jt = 0; jt < (NN/JC)/64; ++jt) {
    int j0 = j0base + jt*64;
    __syncthreads();
    #pragma unroll
    for (int m = 0; m < 2; ++m) {
      int e4 = t + 512*m;
      int jj = e4 >> 4, i4 = (e4 & 15) << 2;
      float4 vv = *reinterpret_cast<const float4*>(adj + ((size_t)b*NN + j0 + jj)*NN + i0 + i4);
      float* dst = &Tjs[jj][i4];
      dst[0] = vv.x; dst[1] = vv.y; dst[2] = vv.z; dst[3] = vv.w;
    }
    const float4* vb = reinterpret_cast<const float4*>(rvec + ((size_t)b*NN + j0 + lane)*8);
    float4 a = vb[0], c = vb[1];
    float vr[NIDX] = {a.x, a.z, c.x, c.z};
    float vi[NIDX] = {a.y, a.w, c.y, c.w};
    __syncthreads();
    const float* arbase = adj + ((size_t)b*NN + i0 + wu*8)*NN + j0 + lane;
    #pragma unroll
    for (int s = 0; s < 8; ++s) {
      float ar = arbase[(size_t)s*NN];
      float ac = Tjs[lane][wu*8 + s];
      float dd = ar - ac, sm = ar + ac;
      __half2 h = __floats2half2_rn(sm, dd);
      smdd[((size_t)b*NN + i0 + wu*8 + s)*NN + j0 + lane] = *reinterpret_cast<unsigned*>(&h);
      float csv[NIDX], snv[NIDX];
      TRIG6(dd, csv, snv)
      #pragma unroll
      for (int x = 0; x < NIDX; ++x) {
        float A = sm*csv[x], B = sm*snv[x];
        accr[s][x] += A*vr[x] - B*vi[x];
        acci[s][x] += A*vi[x] + B*vr[x];
      }
    }
  }
  bool b1 = (lane & 1), b2 = (lane & 2), b4 = (lane & 4);
  TREDUCE(accr, acci, red, w, lane, b1, b2, b4)
  __syncthreads();
  {
    int iloc = w*8 + (lane >> 3), slot = lane & 7;
    float sum = 0.f;
    #pragma unroll
    for (int g = 0; g < 8; ++g) sum += red[w][(lane >> 3)*72 + slot*9 + g];
    int gi = b*NN + i0 + iloc;
    atomicAdd(&wtot[(size_t)gi*8 + slot], sum * 0.5f * dinv[gi]);
  }
}

// Pass 1 (R19-proven streaming structure): out += halfM(dinv_j * wtot).
// Barrier-free; smdd sequential coalesced; dinv_j folded at v-load.
// grid (NB, 32, JC), 256 thr.
__global__ __launch_bounds__(256, 4) void k_pass1(const unsigned* __restrict__ smdd,
                                                  const float* __restrict__ dinv,
                                                  const float* __restrict__ wtot,
                                                  float* __restrict__ out) {
  __shared__ float red[4][8*72];
  int b = blockIdx.x, i0 = blockIdx.y*32, zc = blockIdx.z;
  int t = threadIdx.x, lane = t & 63, w = t >> 6;
  int wu = __builtin_amdgcn_readfirstlane(w);
  int ibase = i0 + wu*8;
  float accr[8][NIDX], acci[8][NIDX];
  #pragma unroll
  for (int s = 0; s < 8; ++s)
    #pragma unroll
    for (int x = 0; x < NIDX; ++x) { accr[s][x] = 0.f; acci[s][x] = 0.f; }

  for (int jt = 0; jt < (NN/JC)/64; ++jt) {
    int jg = zc*(NN/JC) + jt*64 + lane;
    float dj = dinv[b*NN + jg];
    const float4* vp = reinterpret_cast<const float4*>(wtot + ((size_t)b*NN + jg)*8);
    float4 va = vp[0], vb = vp[1];
    float vr[NIDX] = {dj*va.x, dj*va.z, dj*vb.x, dj*vb.z};
    float vi[NIDX] = {dj*va.y, dj*va.w, dj*vb.y, dj*vb.w};
    const unsigned* sp = smdd + ((size_t)b*NN + ibase)*NN + jg;
    #pragma unroll
    for (int s = 0; s < 8; ++s) {
      unsigned wrd = sp[(size_t)s*NN];
      __half2 h = *reinterpret_cast<__half2*>(&wrd);
      float sm = __low2float(h), dd = __high2float(h);
      float csv[NIDX], snv[NIDX];
      TRIG6(dd, csv, snv)
      #pragma unroll
      for (int x = 0; x < NIDX; ++x) {
        float A = sm*csv[x], B = sm*snv[x];
        accr[s][x] += A*vr[x] - B*vi[x];
        acci[s][x] += A*vi[x] + B*vr[x];
      }
    }
  }

  bool b1 = (lane & 1), b2 = (lane & 2), b4 = (lane & 4);
  TREDUCE(accr, acci, red, w, lane, b1, b2, b4)
  __syncthreads();
  {
    int row = lane >> 3, slot = lane & 7;
    float sum = 0.f;
    #pragma unroll
    for (int g = 0; g < 8; ++g) sum += red[w][row*72 + slot*9 + g];
    int gi = b*NN + ibase + row;
    float val = sum * 0.5f * dinv[gi];
    atomicAdd(&out[(slot & 1)*32768 + gi*4 + (slot >> 1)], val);
  }
}

extern "C" void kernel_launch(void* const* d_in, const int* in_sizes, int n_in,
                              void* d_out, int out_size, void* d_ws, size_t ws_size,
                              hipStream_t stream) {
  (void)in_sizes; (void)n_in; (void)out_size; (void)ws_size;
  const float* Xr     = (const float*)d_in[0];
  const float* Xi     = (const float*)d_in[1];
  const float* adj    = (const float*)d_in[2];
  const float* weight = (const float*)d_in[3];
  const float* bias   = (const float*)d_in[4];
  float* ws = (float*)d_ws;
  float* rowsum  = ws + OFF_ROW;
  float* colpart = ws + OFF_COLP;
  float* dinv    = ws + OFF_DINV;
  float* rvec    = ws + OFF_R;
  float* wtot    = ws + OFF_WT;
  unsigned* smdd = (unsigned*)(ws + OFF_SMDD);
  float* out = (float*)d_out;

  k_sums<<<dim3(NB, 64), 512, 0, stream>>>(adj, rowsum, colpart);
  k_prep<<<dim3(NB*NN/256), 256, 0, stream>>>(Xr, Xi, weight, rowsum, colpart, bias,
                                              dinv, rvec, wtot, out);
  k_pass0<<<dim3(NB, NN/64, JC), 512, 0, stream>>>(adj, dinv, rvec, smdd, wtot);
  k_pass1<<<dim3(NB, NN/32, JC), 256, 0, stream>>>(smdd, dinv, wtot, out);
}